// Round 5
// baseline (100.727 us; speedup 1.0000x reference)
//
#include <hip/hip_runtime.h>
#include <math.h>

// Problem constants (from reference setup)
#define NV      6       // views
#define ND      4       // pillar depths
#define NQ      2500    // BEV_H * BEV_W
#define NPATCH  1369    // 37*37 tokens per view
#define CTOK    768     // channels
#define HP      37
#define WP      37
#define CCTX    256
#define QT      4       // queries per block (one wave each)
#define MAXM    96      // max gather entries per query (24 points * 4 corners)

__device__ __forceinline__ float softplus_f(float x) {
    return (x > 20.0f) ? x : log1pf(expf(x));
}

// Single fused kernel: one block = 4 queries, one wave per query.
// Lane l owns CONTIGUOUS channels 12l..12l+11. Since the wave reads the whole
// 768-ch row for every gathered entry anyway, per-row LN stats (mu, rstd) are
// computed in-wave via shfl_xor butterfly — no separate stats pass, no ws.
__global__ __launch_bounds__(256) void bev_fuse_kernel(
    const float* __restrict__ tok,       // (V, NPATCH, CTOK) raw
    const float* __restrict__ lidar2img, // (V,4,4)
    const float* __restrict__ w_view,    // (V)
    const float* __restrict__ gamma,     // (CTOK)
    const float* __restrict__ beta,      // (CTOK)
    const float* __restrict__ logits,    // (CCTX, 3)
    float* __restrict__ out)             // (CCTX, NQ)
{
    __shared__ float s_b[QT][MAXM];      // corner_w * wv
    __shared__ int   s_idx[QT][MAXM];
    __shared__ float s_den[QT][NV * ND];
    __shared__ int   s_cnt[QT];
    __shared__ float s_y[QT][CCTX];

    const int t = threadIdx.x;
    const int q0 = blockIdx.x * QT;

    if (t < QT) s_cnt[t] = 0;
    __syncthreads();

    // ---- projection: threads 0..95, one per (query, v, d) ----
    if (t < QT * NV * ND) {
        const int qi = t / 24;
        const int p  = t - qi * 24;
        const int v = p >> 2, d = p & 3;
        const int q = q0 + qi;
        const int qy = q / 50, qx = q - qy * 50;
        float xf = ((float)qx + 0.5f) * (1.0f / 50.0f);
        float yf = ((float)qy + 0.5f) * (1.0f / 50.0f);
        float zf = (0.5f + (float)d * (7.0f / 3.0f)) * (1.0f / 8.0f);
        float X = xf * 102.4f - 51.2f;
        float Y = yf * 102.4f - 51.2f;
        float Z = zf * 8.0f - 5.0f;
        const float* M = lidar2img + v * 16;
        float px = M[0] * X + M[1] * Y + M[2]  * Z + M[3];
        float py = M[4] * X + M[5] * Y + M[6]  * Z + M[7];
        float pz = M[8] * X + M[9] * Y + M[10] * Z + M[11];
        bool valid = pz > 1e-5f;
        float zc = fmaxf(pz, 1e-5f);
        float uu = px / zc * (1.0f / 518.0f);
        float vv = py / zc * (1.0f / 518.0f);
        valid = valid && (uu > 0.0f) && (uu < 1.0f) && (vv > 0.0f) && (vv < 1.0f);

        float wv = softplus_f(w_view[v]);
        s_den[qi][p] = valid ? wv : 0.0f;

        if (valid) {
            float x_p = (uu * 518.0f + 0.5f) * (37.0f / 518.0f) - 0.5f;
            float y_p = (vv * 518.0f + 0.5f) * (37.0f / 518.0f) - 0.5f;
            float x0f = floorf(x_p), y0f = floorf(y_p);
            float fx = x_p - x0f, fy = y_p - y0f;
            int x0 = (int)x0f, y0 = (int)y0f;
            #pragma unroll
            for (int corner = 0; corner < 4; ++corner) {
                int dx = corner & 1, dy = corner >> 1;
                int xi = x0 + dx, yi = y0 + dy;
                bool inb = (xi >= 0) && (xi < WP) && (yi >= 0) && (yi < HP);
                float w = (dx ? fx : (1.0f - fx)) * (dy ? fy : (1.0f - fy));
                if (inb && w != 0.0f) {
                    int slot = atomicAdd(&s_cnt[qi], 1);
                    s_b[qi][slot]   = w * wv;
                    s_idx[qi][slot] = v * NPATCH + yi * WP + xi;
                }
            }
        }
    }
    __syncthreads();

    const int w = t >> 6, lane = t & 63;
    const int m = s_cnt[w];

    // wave-uniform denominator
    float den = 0.0f;
    #pragma unroll
    for (int p = 0; p < NV * ND; ++p) den += s_den[w][p];

    // ---- gather with in-wave LN stats; 2-row interleave for ILP ----
    const float4* base = (const float4*)tok;
    const int fp = 3 * lane;   // float4 position of this lane's first channel
    float4 a0 = {0,0,0,0}, a1 = {0,0,0,0}, a2 = {0,0,0,0};
    float c0 = 0.0f;
    int j = 0;
    for (; j + 2 <= m; j += 2) {
        float wb0 = s_b[w][j], wb1 = s_b[w][j + 1];
        const float4* p0 = base + (size_t)s_idx[w][j]     * (CTOK / 4) + fp;
        const float4* p1 = base + (size_t)s_idx[w][j + 1] * (CTOK / 4) + fp;
        float4 x0 = p0[0], x1 = p0[1], x2 = p0[2];
        float4 y0 = p1[0], y1 = p1[1], y2 = p1[2];
        float sA  = ((x0.x + x0.y) + (x0.z + x0.w)) + ((x1.x + x1.y) + (x1.z + x1.w))
                  + ((x2.x + x2.y) + (x2.z + x2.w));
        float ssA = x0.x*x0.x + x0.y*x0.y + x0.z*x0.z + x0.w*x0.w
                  + x1.x*x1.x + x1.y*x1.y + x1.z*x1.z + x1.w*x1.w
                  + x2.x*x2.x + x2.y*x2.y + x2.z*x2.z + x2.w*x2.w;
        float sB  = ((y0.x + y0.y) + (y0.z + y0.w)) + ((y1.x + y1.y) + (y1.z + y1.w))
                  + ((y2.x + y2.y) + (y2.z + y2.w));
        float ssB = y0.x*y0.x + y0.y*y0.y + y0.z*y0.z + y0.w*y0.w
                  + y1.x*y1.x + y1.y*y1.y + y1.z*y1.z + y1.w*y1.w
                  + y2.x*y2.x + y2.y*y2.y + y2.z*y2.z + y2.w*y2.w;
        #pragma unroll
        for (int off = 32; off; off >>= 1) {
            sA  += __shfl_xor(sA,  off, 64);
            ssA += __shfl_xor(ssA, off, 64);
            sB  += __shfl_xor(sB,  off, 64);
            ssB += __shfl_xor(ssB, off, 64);
        }
        float muA  = sA * (1.0f / (float)CTOK);
        float varA = ssA * (1.0f / (float)CTOK) - muA * muA;
        float rsA  = rsqrtf(fmaxf(varA, 0.0f) + 1e-5f);
        float muB  = sB * (1.0f / (float)CTOK);
        float varB = ssB * (1.0f / (float)CTOK) - muB * muB;
        float rsB  = rsqrtf(fmaxf(varB, 0.0f) + 1e-5f);
        float b0 = wb0 * rsA, b1 = wb1 * rsB;
        c0 = fmaf(b0, muA, c0);
        c0 = fmaf(b1, muB, c0);
        a0.x = fmaf(b0, x0.x, a0.x); a0.y = fmaf(b0, x0.y, a0.y);
        a0.z = fmaf(b0, x0.z, a0.z); a0.w = fmaf(b0, x0.w, a0.w);
        a1.x = fmaf(b0, x1.x, a1.x); a1.y = fmaf(b0, x1.y, a1.y);
        a1.z = fmaf(b0, x1.z, a1.z); a1.w = fmaf(b0, x1.w, a1.w);
        a2.x = fmaf(b0, x2.x, a2.x); a2.y = fmaf(b0, x2.y, a2.y);
        a2.z = fmaf(b0, x2.z, a2.z); a2.w = fmaf(b0, x2.w, a2.w);
        a0.x = fmaf(b1, y0.x, a0.x); a0.y = fmaf(b1, y0.y, a0.y);
        a0.z = fmaf(b1, y0.z, a0.z); a0.w = fmaf(b1, y0.w, a0.w);
        a1.x = fmaf(b1, y1.x, a1.x); a1.y = fmaf(b1, y1.y, a1.y);
        a1.z = fmaf(b1, y1.z, a1.z); a1.w = fmaf(b1, y1.w, a1.w);
        a2.x = fmaf(b1, y2.x, a2.x); a2.y = fmaf(b1, y2.y, a2.y);
        a2.z = fmaf(b1, y2.z, a2.z); a2.w = fmaf(b1, y2.w, a2.w);
    }
    if (j < m) {
        float wb0 = s_b[w][j];
        const float4* p0 = base + (size_t)s_idx[w][j] * (CTOK / 4) + fp;
        float4 x0 = p0[0], x1 = p0[1], x2 = p0[2];
        float sA  = ((x0.x + x0.y) + (x0.z + x0.w)) + ((x1.x + x1.y) + (x1.z + x1.w))
                  + ((x2.x + x2.y) + (x2.z + x2.w));
        float ssA = x0.x*x0.x + x0.y*x0.y + x0.z*x0.z + x0.w*x0.w
                  + x1.x*x1.x + x1.y*x1.y + x1.z*x1.z + x1.w*x1.w
                  + x2.x*x2.x + x2.y*x2.y + x2.z*x2.z + x2.w*x2.w;
        #pragma unroll
        for (int off = 32; off; off >>= 1) {
            sA  += __shfl_xor(sA,  off, 64);
            ssA += __shfl_xor(ssA, off, 64);
        }
        float muA  = sA * (1.0f / (float)CTOK);
        float varA = ssA * (1.0f / (float)CTOK) - muA * muA;
        float rsA  = rsqrtf(fmaxf(varA, 0.0f) + 1e-5f);
        float b0 = wb0 * rsA;
        c0 = fmaf(b0, muA, c0);
        a0.x = fmaf(b0, x0.x, a0.x); a0.y = fmaf(b0, x0.y, a0.y);
        a0.z = fmaf(b0, x0.z, a0.z); a0.w = fmaf(b0, x0.w, a0.w);
        a1.x = fmaf(b0, x1.x, a1.x); a1.y = fmaf(b0, x1.y, a1.y);
        a1.z = fmaf(b0, x1.z, a1.z); a1.w = fmaf(b0, x1.w, a1.w);
        a2.x = fmaf(b0, x2.x, a2.x); a2.y = fmaf(b0, x2.y, a2.y);
        a2.z = fmaf(b0, x2.z, a2.z); a2.w = fmaf(b0, x2.w, a2.w);
    }

    float f[12];
    {
        float inv = 1.0f / (den + 1e-6f);
        f[0]  = (a0.x - c0) * inv; f[1]  = (a0.y - c0) * inv;
        f[2]  = (a0.z - c0) * inv; f[3]  = (a0.w - c0) * inv;
        f[4]  = (a1.x - c0) * inv; f[5]  = (a1.y - c0) * inv;
        f[6]  = (a1.z - c0) * inv; f[7]  = (a1.w - c0) * inv;
        f[8]  = (a2.x - c0) * inv; f[9]  = (a2.y - c0) * inv;
        f[10] = (a2.z - c0) * inv; f[11] = (a2.w - c0) * inv;
    }

    // ---- post-LN: wave-local reduce over 64 lanes x 12 channels ----
    float s = 0.f, ss = 0.f;
    #pragma unroll
    for (int i = 0; i < 12; ++i) { s += f[i]; ss += f[i] * f[i]; }
    #pragma unroll
    for (int off = 32; off; off >>= 1) {
        s  += __shfl_xor(s,  off, 64);
        ss += __shfl_xor(ss, off, 64);
    }
    float mu  = s * (1.0f / (float)CTOK);
    float var = ss * (1.0f / (float)CTOK) - mu * mu;
    float rs  = rsqrtf(fmaxf(var, 0.0f) + 1e-5f);

    const float4* g4 = (const float4*)gamma;
    const float4* b4 = (const float4*)beta;
    float4 gv[3] = {g4[fp], g4[fp + 1], g4[fp + 2]};
    float4 bv[3] = {b4[fp], b4[fp + 1], b4[fp + 2]};
    const float* gs = (const float*)gv;
    const float* bs = (const float*)bv;
    float h[12];
    #pragma unroll
    for (int i = 0; i < 12; ++i)
        h[i] = (f[i] - mu) * rs * gs[i] + bs[i];

    // ---- group softmax mix: lane l -> output channels 4l..4l+3,
    //      output channel k mixes token channels 3k, 3k+1, 3k+2 ----
    const float4* lg4 = (const float4*)logits;   // (256,3) row-major
    float4 Lv[3] = {lg4[fp], lg4[fp + 1], lg4[fp + 2]};
    const float* lgv = (const float*)Lv;         // logits for channels 4l..4l+3
    #pragma unroll
    for (int jj = 0; jj < 4; ++jj) {
        float l0 = lgv[jj * 3], l1 = lgv[jj * 3 + 1], l2 = lgv[jj * 3 + 2];
        float mx = fmaxf(l0, fmaxf(l1, l2));
        float e0 = expf(l0 - mx), e1 = expf(l1 - mx), e2 = expf(l2 - mx);
        float einv = 1.0f / (e0 + e1 + e2);
        s_y[w][lane * 4 + jj] =
            (h[jj * 3] * e0 + h[jj * 3 + 1] * e1 + h[jj * 3 + 2] * e2) * einv;
    }
    __syncthreads();

    // ---- coalesced store: thread t = channel, float4 of 4 queries ----
    float4 o;
    o.x = s_y[0][t]; o.y = s_y[1][t]; o.z = s_y[2][t]; o.w = s_y[3][t];
    *(float4*)(out + (size_t)t * NQ + q0) = o;
}

extern "C" void kernel_launch(void* const* d_in, const int* in_sizes, int n_in,
                              void* d_out, int out_size, void* d_ws, size_t ws_size,
                              hipStream_t stream) {
    const float* last_tokens = (const float*)d_in[0]; // (1,6,1369,768)
    const float* lidar2img   = (const float*)d_in[1]; // (1,6,4,4)
    const float* w_view      = (const float*)d_in[2]; // (1,6,1)
    const float* post_gamma  = (const float*)d_in[3]; // (768)
    const float* post_beta   = (const float*)d_in[4]; // (768)
    const float* logits      = (const float*)d_in[5]; // (256,3)
    float* out = (float*)d_out;                       // (1,256,50,50)

    bev_fuse_kernel<<<NQ / QT, 256, 0, stream>>>(last_tokens, lidar2img,
                                                 w_view, post_gamma, post_beta,
                                                 logits, out);
}

// Round 6
// 98.062 us; speedup vs baseline: 1.0272x; 1.0272x over previous
//
#include <hip/hip_runtime.h>
#include <math.h>

// Problem constants (from reference setup)
#define NV      6       // views
#define ND      4       // pillar depths
#define NQ      2500    // BEV_H * BEV_W
#define NPATCH  1369    // 37*37 tokens per view
#define NROWS   (NV * NPATCH)  // 8214
#define CTOK    768     // channels
#define HP      37
#define WP      37
#define CCTX    256
#define QT      4       // queries per block (one wave each)
#define MAXM    96      // max gather entries per query (24 points * 4 corners)

__device__ __forceinline__ float softplus_f(float x) {
    return (x > 20.0f) ? x : log1pf(expf(x));
}

// Stage A: per-token LN stats only (mu, rstd). One wave per row, 4 rows/block.
__global__ __launch_bounds__(256) void ln_stats_kernel(
    const float* __restrict__ tok, float* __restrict__ stats /* (NROWS,2) */)
{
    const int wave = threadIdx.x >> 6, lane = threadIdx.x & 63;
    const int row = blockIdx.x * 4 + wave;
    if (row >= NROWS) return;
    const float4* x = (const float4*)(tok + (size_t)row * CTOK);
    float s = 0.f, ss = 0.f;
    #pragma unroll
    for (int i = 0; i < 3; ++i) {           // 768 floats = 64 lanes * 3 float4
        float4 v = x[lane + 64 * i];
        s  += (v.x + v.y) + (v.z + v.w);
        ss += v.x * v.x + v.y * v.y + v.z * v.z + v.w * v.w;
    }
    #pragma unroll
    for (int off = 32; off; off >>= 1) {
        s  += __shfl_down(s,  off, 64);
        ss += __shfl_down(ss, off, 64);
    }
    if (lane == 0) {
        float mu  = s * (1.0f / (float)CTOK);
        float var = ss * (1.0f / (float)CTOK) - mu * mu;
        float rs  = rsqrtf(fmaxf(var, 0.0f) + 1e-5f);
        stats[row * 2 + 0] = mu;
        stats[row * 2 + 1] = rs;
    }
}

#define FMA12(b, r0, r1, r2)                                         \
    a0.x = fmaf(b, r0.x, a0.x); a0.y = fmaf(b, r0.y, a0.y);          \
    a0.z = fmaf(b, r0.z, a0.z); a0.w = fmaf(b, r0.w, a0.w);          \
    a1.x = fmaf(b, r1.x, a1.x); a1.y = fmaf(b, r1.y, a1.y);          \
    a1.z = fmaf(b, r1.z, a1.z); a1.w = fmaf(b, r1.w, a1.w);          \
    a2.x = fmaf(b, r2.x, a2.x); a2.y = fmaf(b, r2.y, a2.y);          \
    a2.z = fmaf(b, r2.z, a2.z); a2.w = fmaf(b, r2.w, a2.w);

// Stage B: one block = 4 queries, one wave per query.
// Lane l owns CONTIGUOUS channels 12l..12l+11 of its query, so the group
// softmax (output channel k mixes token channels 3k,3k+1,3k+2) is lane-local.
__global__ __launch_bounds__(256) void bev_fuse_kernel(
    const float* __restrict__ tok,       // (V, NPATCH, CTOK) raw
    const float* __restrict__ stats,     // (NROWS, 2) mu, rstd
    const float* __restrict__ lidar2img, // (V,4,4)
    const float* __restrict__ w_view,    // (V)
    const float* __restrict__ gamma,     // (CTOK)
    const float* __restrict__ beta,      // (CTOK)
    const float* __restrict__ logits,    // (CCTX, 3)
    float* __restrict__ out)             // (CCTX, NQ)
{
    __shared__ float s_b[QT][MAXM];
    __shared__ float s_bmu[QT][MAXM];
    __shared__ int   s_idx[QT][MAXM];
    __shared__ float s_den[QT][NV * ND];
    __shared__ int   s_cnt[QT];
    __shared__ float s_y[QT][CCTX];

    const int t = threadIdx.x;
    const int q0 = blockIdx.x * QT;

    if (t < QT) s_cnt[t] = 0;
    __syncthreads();

    // ---- projection: threads 0..95, one per (query, v, d) ----
    if (t < QT * NV * ND) {
        const int qi = t / 24;
        const int p  = t - qi * 24;
        const int v = p >> 2, d = p & 3;
        const int q = q0 + qi;
        const int qy = q / 50, qx = q - qy * 50;
        float xf = ((float)qx + 0.5f) * (1.0f / 50.0f);
        float yf = ((float)qy + 0.5f) * (1.0f / 50.0f);
        float zf = (0.5f + (float)d * (7.0f / 3.0f)) * (1.0f / 8.0f);
        float X = xf * 102.4f - 51.2f;
        float Y = yf * 102.4f - 51.2f;
        float Z = zf * 8.0f - 5.0f;
        const float* M = lidar2img + v * 16;
        float px = M[0] * X + M[1] * Y + M[2]  * Z + M[3];
        float py = M[4] * X + M[5] * Y + M[6]  * Z + M[7];
        float pz = M[8] * X + M[9] * Y + M[10] * Z + M[11];
        bool valid = pz > 1e-5f;
        float zc = fmaxf(pz, 1e-5f);
        float uu = px / zc * (1.0f / 518.0f);
        float vv = py / zc * (1.0f / 518.0f);
        valid = valid && (uu > 0.0f) && (uu < 1.0f) && (vv > 0.0f) && (vv < 1.0f);

        float wv = softplus_f(w_view[v]);
        s_den[qi][p] = valid ? wv : 0.0f;

        if (valid) {
            float x_p = (uu * 518.0f + 0.5f) * (37.0f / 518.0f) - 0.5f;
            float y_p = (vv * 518.0f + 0.5f) * (37.0f / 518.0f) - 0.5f;
            float x0f = floorf(x_p), y0f = floorf(y_p);
            float fx = x_p - x0f, fy = y_p - y0f;
            int x0 = (int)x0f, y0 = (int)y0f;
            #pragma unroll
            for (int corner = 0; corner < 4; ++corner) {
                int dx = corner & 1, dy = corner >> 1;
                int xi = x0 + dx, yi = y0 + dy;
                bool inb = (xi >= 0) && (xi < WP) && (yi >= 0) && (yi < HP);
                float w = (dx ? fx : (1.0f - fx)) * (dy ? fy : (1.0f - fy));
                if (inb && w != 0.0f) {
                    int idx = v * NPATCH + yi * WP + xi;
                    float b = w * wv * stats[idx * 2 + 1];
                    int slot = atomicAdd(&s_cnt[qi], 1);
                    s_b[qi][slot]   = b;
                    s_bmu[qi][slot] = b * stats[idx * 2 + 0];
                    s_idx[qi][slot] = idx;
                }
            }
        }
    }
    __syncthreads();

    const int w = t >> 6, lane = t & 63;
    const int m = s_cnt[w];

    // wave-uniform scalars
    float den = 0.0f;
    #pragma unroll
    for (int p = 0; p < NV * ND; ++p) den += s_den[w][p];
    float c0 = 0.0f;
    for (int j = 0; j < m; ++j) c0 += s_bmu[w][j];

    // ---- gather: lane owns float4s 3l..3l+2 of each row; unroll x4 for MLP ----
    const float4* base = (const float4*)tok;
    const int fp = 3 * lane;   // float4 position of this lane's first channel
    float4 a0 = {0,0,0,0}, a1 = {0,0,0,0}, a2 = {0,0,0,0};
    int j = 0;
    for (; j + 4 <= m; j += 4) {
        float b0 = s_b[w][j], b1 = s_b[w][j + 1];
        float b2 = s_b[w][j + 2], b3 = s_b[w][j + 3];
        const float4* p0 = base + (size_t)s_idx[w][j]     * (CTOK / 4) + fp;
        const float4* p1 = base + (size_t)s_idx[w][j + 1] * (CTOK / 4) + fp;
        const float4* p2 = base + (size_t)s_idx[w][j + 2] * (CTOK / 4) + fp;
        const float4* p3 = base + (size_t)s_idx[w][j + 3] * (CTOK / 4) + fp;
        float4 x0 = p0[0], x1 = p0[1], x2 = p0[2];
        float4 y0 = p1[0], y1 = p1[1], y2 = p1[2];
        float4 z0 = p2[0], z1 = p2[1], z2 = p2[2];
        float4 u0 = p3[0], u1 = p3[1], u2 = p3[2];
        FMA12(b0, x0, x1, x2)
        FMA12(b1, y0, y1, y2)
        FMA12(b2, z0, z1, z2)
        FMA12(b3, u0, u1, u2)
    }
    for (; j < m; ++j) {
        float b0 = s_b[w][j];
        const float4* p0 = base + (size_t)s_idx[w][j] * (CTOK / 4) + fp;
        float4 x0 = p0[0], x1 = p0[1], x2 = p0[2];
        FMA12(b0, x0, x1, x2)
    }

    float f[12];
    {
        float inv = 1.0f / (den + 1e-6f);
        f[0]  = (a0.x - c0) * inv; f[1]  = (a0.y - c0) * inv;
        f[2]  = (a0.z - c0) * inv; f[3]  = (a0.w - c0) * inv;
        f[4]  = (a1.x - c0) * inv; f[5]  = (a1.y - c0) * inv;
        f[6]  = (a1.z - c0) * inv; f[7]  = (a1.w - c0) * inv;
        f[8]  = (a2.x - c0) * inv; f[9]  = (a2.y - c0) * inv;
        f[10] = (a2.z - c0) * inv; f[11] = (a2.w - c0) * inv;
    }

    // ---- post-LN: wave-local reduce over 64 lanes x 12 channels ----
    float s = 0.f, ss = 0.f;
    #pragma unroll
    for (int i = 0; i < 12; ++i) { s += f[i]; ss += f[i] * f[i]; }
    #pragma unroll
    for (int off = 32; off; off >>= 1) {
        s  += __shfl_xor(s,  off, 64);
        ss += __shfl_xor(ss, off, 64);
    }
    float mu  = s * (1.0f / (float)CTOK);
    float var = ss * (1.0f / (float)CTOK) - mu * mu;
    float rs  = rsqrtf(fmaxf(var, 0.0f) + 1e-5f);

    const float4* g4 = (const float4*)gamma;
    const float4* b4 = (const float4*)beta;
    float4 gv[3] = {g4[fp], g4[fp + 1], g4[fp + 2]};
    float4 bv[3] = {b4[fp], b4[fp + 1], b4[fp + 2]};
    const float* gs = (const float*)gv;
    const float* bs = (const float*)bv;
    float h[12];
    #pragma unroll
    for (int i = 0; i < 12; ++i)
        h[i] = (f[i] - mu) * rs * gs[i] + bs[i];

    // ---- group softmax mix: lane l -> output channels 4l..4l+3 ----
    const float4* lg4 = (const float4*)logits;   // (256,3) row-major
    float4 Lv[3] = {lg4[fp], lg4[fp + 1], lg4[fp + 2]};
    const float* lgv = (const float*)Lv;         // logits for channels 4l..4l+3
    #pragma unroll
    for (int jj = 0; jj < 4; ++jj) {
        float l0 = lgv[jj * 3], l1 = lgv[jj * 3 + 1], l2 = lgv[jj * 3 + 2];
        float mx = fmaxf(l0, fmaxf(l1, l2));
        float e0 = expf(l0 - mx), e1 = expf(l1 - mx), e2 = expf(l2 - mx);
        float einv = 1.0f / (e0 + e1 + e2);
        s_y[w][lane * 4 + jj] =
            (h[jj * 3] * e0 + h[jj * 3 + 1] * e1 + h[jj * 3 + 2] * e2) * einv;
    }
    __syncthreads();

    // ---- coalesced store: thread t = channel, float4 of 4 queries ----
    float4 o;
    o.x = s_y[0][t]; o.y = s_y[1][t]; o.z = s_y[2][t]; o.w = s_y[3][t];
    *(float4*)(out + (size_t)t * NQ + q0) = o;
}

extern "C" void kernel_launch(void* const* d_in, const int* in_sizes, int n_in,
                              void* d_out, int out_size, void* d_ws, size_t ws_size,
                              hipStream_t stream) {
    const float* last_tokens = (const float*)d_in[0]; // (1,6,1369,768)
    const float* lidar2img   = (const float*)d_in[1]; // (1,6,4,4)
    const float* w_view      = (const float*)d_in[2]; // (1,6,1)
    const float* post_gamma  = (const float*)d_in[3]; // (768)
    const float* post_beta   = (const float*)d_in[4]; // (768)
    const float* logits      = (const float*)d_in[5]; // (256,3)
    float* out = (float*)d_out;                       // (1,256,50,50)

    float* stats = (float*)d_ws;                      // 8214*2 floats = 64 KB

    ln_stats_kernel<<<(NROWS + 3) / 4, 256, 0, stream>>>(last_tokens, stats);
    bev_fuse_kernel<<<NQ / QT, 256, 0, stream>>>(last_tokens, stats, lidar2img,
                                                 w_view, post_gamma, post_beta,
                                                 logits, out);
}